// Round 1
// baseline (189.574 us; speedup 1.0000x reference)
//
#include <hip/hip_runtime.h>

// Problem constants
#define BATCH 4
#define SEQ   2048
#define INC   512
#define NH    8
#define OUTC  64      // space dim; head dim = 65
#define DD    65

typedef float f32x4 __attribute__((ext_vector_type(4)));
typedef short short8 __attribute__((ext_vector_type(8)));

static __device__ __forceinline__ unsigned short f2b(float f) {
  unsigned int u = __float_as_uint(f);
  u = (u + 0x7FFFu + ((u >> 16) & 1u)) >> 16;   // RNE f32->bf16
  return (unsigned short)u;
}

// ---------------------------------------------------------------------------
// Kernel 1: per-head projections.  For z=0: Q from query_input; z=1: K, z=2: V
// from source_input.  sp[s, h*64+o] = sum_i X[s,i] * W[h*64+o, i] + b
// Writes sp as bf16 [B,H,S,64] and t = sqrt(|sp|^2+1) as f32 [B,H,S].
// 64x64 output tile per block, K-loop of 64, MFMA 16x16x32 bf16.
// ---------------------------------------------------------------------------
__global__ __launch_bounds__(256) void proj_kernel(
    const float* __restrict__ Xq, const float* __restrict__ Xs,
    const float* __restrict__ Wq, const float* __restrict__ Wqb,
    const float* __restrict__ Wk, const float* __restrict__ Wkb,
    const float* __restrict__ Wv, const float* __restrict__ Wvb,
    unsigned short* __restrict__ qs, float* __restrict__ qt,
    unsigned short* __restrict__ ks, float* __restrict__ kt,
    unsigned short* __restrict__ vs, float* __restrict__ vt)
{
  const int which = blockIdx.z;
  const float* X  = (which == 0) ? Xq : Xs;
  const float* W  = (which == 0) ? Wq : (which == 1 ? Wk : Wv);
  const float* Bb = (which == 0) ? Wqb : (which == 1 ? Wkb : Wvb);
  unsigned short* outs = (which == 0) ? qs : (which == 1 ? ks : vs);
  float* outt = (which == 0) ? qt : (which == 1 ? kt : vt);

  const int m0 = blockIdx.x * 64;   // row block in [0, B*S)
  const int h  = blockIdx.y;        // head == 64-col block of N=512
  const int n0 = h * 64;

  __shared__ alignas(16) unsigned short lX[64 * 64];
  __shared__ alignas(16) unsigned short lW[64 * 64];

  const int tid  = threadIdx.x;
  const int lane = tid & 63;
  const int wave = tid >> 6;
  const int arow = lane & 15;
  const int agrp = lane >> 4;

  f32x4 acc[4] = {};

  for (int k0 = 0; k0 < INC; k0 += 64) {
    __syncthreads();
#pragma unroll
    for (int u0 = 0; u0 < 2; ++u0) {
      int u = tid + u0 * 256;               // 512 units: 64 rows x 8 chunks
      int row = u >> 3, ch = u & 7;
      int slot = ch ^ (row & 7);            // XOR swizzle (16B granules)
      {
        const f32x4* src = (const f32x4*)(X + (size_t)(m0 + row) * INC + k0 + ch * 8);
        f32x4 a = src[0], b = src[1];
        short8 p;
        p[0]=f2b(a[0]); p[1]=f2b(a[1]); p[2]=f2b(a[2]); p[3]=f2b(a[3]);
        p[4]=f2b(b[0]); p[5]=f2b(b[1]); p[6]=f2b(b[2]); p[7]=f2b(b[3]);
        *(short8*)&lX[row * 64 + slot * 8] = p;
      }
      {
        const f32x4* src = (const f32x4*)(W + (size_t)(n0 + row) * INC + k0 + ch * 8);
        f32x4 a = src[0], b = src[1];
        short8 p;
        p[0]=f2b(a[0]); p[1]=f2b(a[1]); p[2]=f2b(a[2]); p[3]=f2b(a[3]);
        p[4]=f2b(b[0]); p[5]=f2b(b[1]); p[6]=f2b(b[2]); p[7]=f2b(b[3]);
        *(short8*)&lW[row * 64 + slot * 8] = p;
      }
    }
    __syncthreads();
#pragma unroll
    for (int kc = 0; kc < 2; ++kc) {
      short8 af = *(const short8*)&lX[(wave * 16 + arow) * 64 + (((kc * 4 + agrp) ^ (arow & 7)) * 8)];
#pragma unroll
      for (int c = 0; c < 4; ++c) {
        short8 bf = *(const short8*)&lW[(c * 16 + arow) * 64 + (((kc * 4 + agrp) ^ (arow & 7)) * 8)];
        acc[c] = __builtin_amdgcn_mfma_f32_16x16x32_bf16(af, bf, acc[c], 0, 0, 0);
      }
    }
  }

  // epilogue: bias, t = sqrt(rowsum(sp^2)+1), writes
  float bcol[4];
#pragma unroll
  for (int c = 0; c < 4; ++c) bcol[c] = Bb[n0 + c * 16 + arow];
#pragma unroll
  for (int r = 0; r < 4; ++r) {
    float s2 = 0.f;
#pragma unroll
    for (int c = 0; c < 4; ++c) {
      float v = acc[c][r] + bcol[c];
      acc[c][r] = v;
      s2 += v * v;
    }
    s2 += __shfl_xor(s2, 1); s2 += __shfl_xor(s2, 2);
    s2 += __shfl_xor(s2, 4); s2 += __shfl_xor(s2, 8);
    float tv = sqrtf(s2 + 1.0f);
    int gs = m0 + wave * 16 + agrp * 4 + r;
    int bi = gs >> 11, si = gs & (SEQ - 1);
    size_t rowbase = (size_t)(bi * NH + h) * SEQ + si;
    size_t obase = rowbase * 64;
#pragma unroll
    for (int c = 0; c < 4; ++c) outs[obase + c * 16 + arow] = f2b(acc[c][r]);
    if (arow == 0) outt[rowbase] = tv;
  }
}

// ---------------------------------------------------------------------------
// Kernel 2: transpose V space-part per (b,h): [S,64] -> [64,S]  (bf16)
// ---------------------------------------------------------------------------
__global__ __launch_bounds__(256) void transpose_v_kernel(
    const unsigned short* __restrict__ vs, unsigned short* __restrict__ vT)
{
  const int bh = blockIdx.y;
  const int s0 = blockIdx.x * 64;
  __shared__ unsigned short lT[64 * 80];   // padded rows (160B, 16B-aligned)
  const int tid = threadIdx.x;
#pragma unroll
  for (int u0 = 0; u0 < 2; ++u0) {
    int u = tid + u0 * 256;
    int row = u >> 3, ch = u & 7;
    short8 v = *(const short8*)&vs[((size_t)bh * SEQ + s0 + row) * 64 + ch * 8];
    *(short8*)&lT[row * 80 + ch * 8] = v;
  }
  __syncthreads();
#pragma unroll
  for (int u0 = 0; u0 < 2; ++u0) {
    int u = tid + u0 * 256;
    int o = u >> 3, sc = u & 7;
    short8 w;
#pragma unroll
    for (int j = 0; j < 8; ++j) w[j] = lT[(sc * 8 + j) * 80 + o];
    *(short8*)&vT[((size_t)bh * 64 + o) * SEQ + s0 + sc * 8] = w;
  }
}

// ---------------------------------------------------------------------------
// Kernel 3: causal flash attention with Lorentzian logits.
// logit = a*(qs.ks) - a*qt*kt, a = 2/scale (row-constants dropped).
// Block = (b,h, 64-row q tile), 4 waves x 16 rows. KBLK = 64.
// Writes ctx f32 [B,H,S,65] (d=0 is time coord).
// ---------------------------------------------------------------------------
__global__ __launch_bounds__(256) void attn_kernel(
    const unsigned short* __restrict__ qs, const float* __restrict__ qt,
    const unsigned short* __restrict__ ks, const float* __restrict__ ktm,
    const unsigned short* __restrict__ vT, const float* __restrict__ vtm,
    const float* __restrict__ scale_p, float* __restrict__ ctx)
{
  const int qb = blockIdx.x;
  const int bh = blockIdx.y;
  const int q0 = qb * 64;
  const float a = 2.0f / scale_p[0];

  __shared__ alignas(16) unsigned short lK[64 * 64];       // K tile [k][d]
  __shared__ alignas(16) unsigned short lV[64 * 64];       // V^T tile [d][k]
  __shared__ alignas(16) unsigned short lP[4][16 * 64];    // per-wave P tile
  __shared__ float lkt[64];
  __shared__ float lvt[64];

  const int tid  = threadIdx.x;
  const int lane = tid & 63;
  const int wave = tid >> 6;
  const int arow = lane & 15;
  const int agrp = lane >> 4;

  const size_t bhbase = (size_t)bh * SEQ;

  short8 qf[2];
  {
    const unsigned short* qp = qs + (bhbase + q0 + wave * 16 + arow) * 64;
    qf[0] = *(const short8*)(qp + agrp * 8);
    qf[1] = *(const short8*)(qp + 32 + agrp * 8);
  }
  float aqt[4];
#pragma unroll
  for (int r = 0; r < 4; ++r)
    aqt[r] = a * qt[bhbase + q0 + wave * 16 + agrp * 4 + r];

  float m[4], lsum[4], ctxt[4];
  f32x4 acc[4] = {};
#pragma unroll
  for (int r = 0; r < 4; ++r) { m[r] = -1e30f; lsum[r] = 0.f; ctxt[r] = 0.f; }

  for (int kti = 0; kti <= qb; ++kti) {
    const int k0 = kti * 64;
    __syncthreads();
#pragma unroll
    for (int u0 = 0; u0 < 2; ++u0) {
      int u = tid + u0 * 256;
      int row = u >> 3, ch = u & 7;
      int slot = ch ^ (row & 7);
      *(short8*)&lK[row * 64 + slot * 8] =
          *(const short8*)&ks[(bhbase + k0 + row) * 64 + ch * 8];
      *(short8*)&lV[row * 64 + slot * 8] =
          *(const short8*)&vT[((size_t)bh * 64 + row) * SEQ + k0 + ch * 8];
    }
    if (tid < 64)       lkt[tid]      = ktm[bhbase + k0 + tid];
    else if (tid < 128) lvt[tid - 64] = vtm[bhbase + k0 + tid - 64];
    __syncthreads();

    // S = Q K^T (64-dim space part)
    f32x4 s[4] = {};
#pragma unroll
    for (int kc = 0; kc < 2; ++kc) {
#pragma unroll
      for (int c = 0; c < 4; ++c) {
        short8 kf = *(const short8*)&lK[(c * 16 + arow) * 64 + (((kc * 4 + agrp) ^ (arow & 7)) * 8)];
        s[c] = __builtin_amdgcn_mfma_f32_16x16x32_bf16(qf[kc], kf, s[c], 0, 0, 0);
      }
    }
    float ktc[4], vtc[4];
#pragma unroll
    for (int c = 0; c < 4; ++c) { ktc[c] = lkt[c * 16 + arow]; vtc[c] = lvt[c * 16 + arow]; }
#pragma unroll
    for (int c = 0; c < 4; ++c)
#pragma unroll
      for (int r = 0; r < 4; ++r)
        s[c][r] = a * s[c][r] - aqt[r] * ktc[c];
    if (kti == qb) {  // diagonal tile: mask k>q
#pragma unroll
      for (int c = 0; c < 4; ++c)
#pragma unroll
        for (int r = 0; r < 4; ++r)
          if (c * 16 + arow > wave * 16 + agrp * 4 + r) s[c][r] = -1e30f;
    }

    // online softmax (row lives in a 16-lane group)
    float fac[4];
#pragma unroll
    for (int r = 0; r < 4; ++r) {
      float mx = fmaxf(fmaxf(s[0][r], s[1][r]), fmaxf(s[2][r], s[3][r]));
      mx = fmaxf(mx, __shfl_xor(mx, 1));
      mx = fmaxf(mx, __shfl_xor(mx, 2));
      mx = fmaxf(mx, __shfl_xor(mx, 4));
      mx = fmaxf(mx, __shfl_xor(mx, 8));
      float mn = fmaxf(m[r], mx);
      fac[r] = __expf(m[r] - mn);
      m[r] = mn;
    }
    float psum[4] = {0.f, 0.f, 0.f, 0.f};
    float ptp[4]  = {0.f, 0.f, 0.f, 0.f};
#pragma unroll
    for (int c = 0; c < 4; ++c)
#pragma unroll
      for (int r = 0; r < 4; ++r) {
        float p = __expf(s[c][r] - m[r]);
        s[c][r] = p;
        psum[r] += p;
        ptp[r] += p * vtc[c];
      }
#pragma unroll
    for (int r = 0; r < 4; ++r) {
      psum[r] += __shfl_xor(psum[r], 1);
      psum[r] += __shfl_xor(psum[r], 2);
      psum[r] += __shfl_xor(psum[r], 4);
      psum[r] += __shfl_xor(psum[r], 8);
      lsum[r] = lsum[r] * fac[r] + psum[r];
      ctxt[r] = ctxt[r] * fac[r] + ptp[r];
#pragma unroll
      for (int dc = 0; dc < 4; ++dc) acc[dc][r] *= fac[r];
    }

    // P -> wave-private LDS (bf16, swizzled), then PV MFMAs
    unsigned short* myP = &lP[wave][0];
#pragma unroll
    for (int c = 0; c < 4; ++c)
#pragma unroll
      for (int r = 0; r < 4; ++r) {
        int prow = agrp * 4 + r;
        int pcol = c * 16 + arow;
        myP[prow * 64 + (((pcol >> 3) ^ (prow & 7)) * 8) + (pcol & 7)] = f2b(s[c][r]);
      }
#pragma unroll
    for (int kc = 0; kc < 2; ++kc) {
      short8 pf = *(const short8*)&myP[arow * 64 + (((kc * 4 + agrp) ^ (arow & 7)) * 8)];
#pragma unroll
      for (int dc = 0; dc < 4; ++dc) {
        short8 vf = *(const short8*)&lV[(dc * 16 + arow) * 64 + (((kc * 4 + agrp) ^ (arow & 7)) * 8)];
        acc[dc] = __builtin_amdgcn_mfma_f32_16x16x32_bf16(pf, vf, acc[dc], 0, 0, 0);
      }
    }
  }

  // epilogue: normalize by lsum, write ctx [B,H,S,65]
#pragma unroll
  for (int r = 0; r < 4; ++r) {
    ctxt[r] += __shfl_xor(ctxt[r], 1);
    ctxt[r] += __shfl_xor(ctxt[r], 2);
    ctxt[r] += __shfl_xor(ctxt[r], 4);
    ctxt[r] += __shfl_xor(ctxt[r], 8);
    float inv = 1.0f / lsum[r];
    size_t rb = (bhbase + q0 + wave * 16 + agrp * 4 + r) * (size_t)DD;
    if (arow == 0) ctx[rb] = ctxt[r] * inv;
#pragma unroll
    for (int dc = 0; dc < 4; ++dc)
      ctx[rb + 1 + dc * 16 + arow] = acc[dc][r] * inv;
  }
}

// ---------------------------------------------------------------------------
// Kernel 4: mean over heads + Lorentz normalization. One wave per (b,s).
// ---------------------------------------------------------------------------
__global__ __launch_bounds__(256) void finalize_kernel(
    const float* __restrict__ ctx, float* __restrict__ out)
{
  const int tid  = threadIdx.x;
  const int lane = tid & 63;
  const int gw = blockIdx.x * 4 + (tid >> 6);
  const int b = gw >> 11, si = gw & (SEQ - 1);
  float v = 0.f, v64 = 0.f;
#pragma unroll
  for (int h = 0; h < NH; ++h) {
    size_t base = ((size_t)(b * NH + h) * SEQ + si) * (size_t)DD;
    v += ctx[base + lane];
    if (lane == 0) v64 += ctx[base + 64];
  }
  float ave   = v * 0.125f;
  float ave64 = v64 * 0.125f;
  float contrib = (lane == 0) ? (ave64 * ave64 - ave * ave) : ave * ave;
  contrib += __shfl_xor(contrib, 1);
  contrib += __shfl_xor(contrib, 2);
  contrib += __shfl_xor(contrib, 4);
  contrib += __shfl_xor(contrib, 8);
  contrib += __shfl_xor(contrib, 16);
  contrib += __shfl_xor(contrib, 32);
  float denom = sqrtf(fmaxf(fabsf(contrib), 1e-8f));
  size_t ob = ((size_t)b * SEQ + si) * (size_t)DD;
  out[ob + lane] = ave / denom;
  if (lane == 0) out[ob + 64] = ave64 / denom;
}

// ---------------------------------------------------------------------------
extern "C" void kernel_launch(void* const* d_in, const int* in_sizes, int n_in,
                              void* d_out, int out_size, void* d_ws, size_t ws_size,
                              hipStream_t stream) {
  const float* Xq  = (const float*)d_in[0];
  const float* Xs  = (const float*)d_in[1];
  const float* Wq  = (const float*)d_in[2];
  const float* Wqb = (const float*)d_in[3];
  const float* Wk  = (const float*)d_in[4];
  const float* Wkb = (const float*)d_in[5];
  const float* Wv  = (const float*)d_in[6];
  const float* Wvb = (const float*)d_in[7];
  const float* scale = (const float*)d_in[8];
  float* out = (float*)d_out;

  char* ws = (char*)d_ws;
  const size_t NROW = (size_t)BATCH * NH * SEQ;   // 65536
  unsigned short* qsb = (unsigned short*)ws; ws += NROW * 64 * 2;
  unsigned short* ksb = (unsigned short*)ws; ws += NROW * 64 * 2;
  unsigned short* vsb = (unsigned short*)ws; ws += NROW * 64 * 2;
  unsigned short* vTb = (unsigned short*)ws; ws += NROW * 64 * 2;
  float* qtb = (float*)ws; ws += NROW * 4;
  float* ktb = (float*)ws; ws += NROW * 4;
  float* vtb = (float*)ws; ws += NROW * 4;
  float* ctx = (float*)ws; ws += NROW * (size_t)DD * 4;

  proj_kernel<<<dim3(128, NH, 3), 256, 0, stream>>>(
      Xq, Xs, Wq, Wqb, Wk, Wkb, Wv, Wvb, qsb, qtb, ksb, ktb, vsb, vtb);
  transpose_v_kernel<<<dim3(SEQ / 64, BATCH * NH), 256, 0, stream>>>(vsb, vTb);
  attn_kernel<<<dim3(SEQ / 64, BATCH * NH), 256, 0, stream>>>(
      qsb, qtb, ksb, ktb, vTb, vtb, scale, ctx);
  finalize_kernel<<<(BATCH * SEQ) / 4, 256, 0, stream>>>(ctx, out);
}

// Round 2
// 113.402 us; speedup vs baseline: 1.6717x; 1.6717x over previous
//
#include <hip/hip_runtime.h>

// Problem constants
#define BATCH 4
#define SEQ   2048
#define INC   512
#define NH    8
#define OUTC  64      // space dim; head dim = 65
#define DD    65

typedef float f32x4 __attribute__((ext_vector_type(4)));
typedef short short8 __attribute__((ext_vector_type(8)));

static __device__ __forceinline__ unsigned short f2b(float f) {
  unsigned int u = __float_as_uint(f);
  u = (u + 0x7FFFu + ((u >> 16) & 1u)) >> 16;   // RNE f32->bf16
  return (unsigned short)u;
}

static __device__ __forceinline__ unsigned int pk2(float lo, float hi) {
  unsigned int r;
  asm("v_cvt_pk_bf16_f32 %0, %1, %2" : "=v"(r) : "v"(lo), "v"(hi));
  return r;
}

#define GLDS(g, l) __builtin_amdgcn_global_load_lds( \
    (const __attribute__((address_space(1))) void*)(g), \
    (__attribute__((address_space(3))) void*)(l), 16, 0, 0)

// ---------------------------------------------------------------------------
// Kernel 1: per-head projections (unchanged from passing round).
// ---------------------------------------------------------------------------
__global__ __launch_bounds__(256) void proj_kernel(
    const float* __restrict__ Xq, const float* __restrict__ Xs,
    const float* __restrict__ Wq, const float* __restrict__ Wqb,
    const float* __restrict__ Wk, const float* __restrict__ Wkb,
    const float* __restrict__ Wv, const float* __restrict__ Wvb,
    unsigned short* __restrict__ qs, float* __restrict__ qt,
    unsigned short* __restrict__ ks, float* __restrict__ kt,
    unsigned short* __restrict__ vs, float* __restrict__ vt)
{
  const int which = blockIdx.z;
  const float* X  = (which == 0) ? Xq : Xs;
  const float* W  = (which == 0) ? Wq : (which == 1 ? Wk : Wv);
  const float* Bb = (which == 0) ? Wqb : (which == 1 ? Wkb : Wvb);
  unsigned short* outs = (which == 0) ? qs : (which == 1 ? ks : vs);
  float* outt = (which == 0) ? qt : (which == 1 ? kt : vt);

  const int m0 = blockIdx.x * 64;
  const int h  = blockIdx.y;
  const int n0 = h * 64;

  __shared__ alignas(16) unsigned short lX[64 * 64];
  __shared__ alignas(16) unsigned short lW[64 * 64];

  const int tid  = threadIdx.x;
  const int lane = tid & 63;
  const int wave = tid >> 6;
  const int arow = lane & 15;
  const int agrp = lane >> 4;

  f32x4 acc[4] = {};

  for (int k0 = 0; k0 < INC; k0 += 64) {
    __syncthreads();
#pragma unroll
    for (int u0 = 0; u0 < 2; ++u0) {
      int u = tid + u0 * 256;
      int row = u >> 3, ch = u & 7;
      int slot = ch ^ (row & 7);
      {
        const f32x4* src = (const f32x4*)(X + (size_t)(m0 + row) * INC + k0 + ch * 8);
        f32x4 a = src[0], b = src[1];
        short8 p;
        p[0]=f2b(a[0]); p[1]=f2b(a[1]); p[2]=f2b(a[2]); p[3]=f2b(a[3]);
        p[4]=f2b(b[0]); p[5]=f2b(b[1]); p[6]=f2b(b[2]); p[7]=f2b(b[3]);
        *(short8*)&lX[row * 64 + slot * 8] = p;
      }
      {
        const f32x4* src = (const f32x4*)(W + (size_t)(n0 + row) * INC + k0 + ch * 8);
        f32x4 a = src[0], b = src[1];
        short8 p;
        p[0]=f2b(a[0]); p[1]=f2b(a[1]); p[2]=f2b(a[2]); p[3]=f2b(a[3]);
        p[4]=f2b(b[0]); p[5]=f2b(b[1]); p[6]=f2b(b[2]); p[7]=f2b(b[3]);
        *(short8*)&lW[row * 64 + slot * 8] = p;
      }
    }
    __syncthreads();
#pragma unroll
    for (int kc = 0; kc < 2; ++kc) {
      short8 af = *(const short8*)&lX[(wave * 16 + arow) * 64 + (((kc * 4 + agrp) ^ (arow & 7)) * 8)];
#pragma unroll
      for (int c = 0; c < 4; ++c) {
        short8 bf = *(const short8*)&lW[(c * 16 + arow) * 64 + (((kc * 4 + agrp) ^ (arow & 7)) * 8)];
        acc[c] = __builtin_amdgcn_mfma_f32_16x16x32_bf16(af, bf, acc[c], 0, 0, 0);
      }
    }
  }

  float bcol[4];
#pragma unroll
  for (int c = 0; c < 4; ++c) bcol[c] = Bb[n0 + c * 16 + arow];
#pragma unroll
  for (int r = 0; r < 4; ++r) {
    float s2 = 0.f;
#pragma unroll
    for (int c = 0; c < 4; ++c) {
      float v = acc[c][r] + bcol[c];
      acc[c][r] = v;
      s2 += v * v;
    }
    s2 += __shfl_xor(s2, 1); s2 += __shfl_xor(s2, 2);
    s2 += __shfl_xor(s2, 4); s2 += __shfl_xor(s2, 8);
    float tv = sqrtf(s2 + 1.0f);
    int gs = m0 + wave * 16 + agrp * 4 + r;
    int bi = gs >> 11, si = gs & (SEQ - 1);
    size_t rowbase = (size_t)(bi * NH + h) * SEQ + si;
    size_t obase = rowbase * 64;
#pragma unroll
    for (int c = 0; c < 4; ++c) outs[obase + c * 16 + arow] = f2b(acc[c][r]);
    if (arow == 0) outt[rowbase] = tv;
  }
}

// ---------------------------------------------------------------------------
// Kernel 2: transpose V space-part per (b,h): [S,64] -> [64,S]  (bf16)
// ---------------------------------------------------------------------------
__global__ __launch_bounds__(256) void transpose_v_kernel(
    const unsigned short* __restrict__ vs, unsigned short* __restrict__ vT)
{
  const int bh = blockIdx.y;
  const int s0 = blockIdx.x * 64;
  __shared__ unsigned short lT[64 * 80];
  const int tid = threadIdx.x;
#pragma unroll
  for (int u0 = 0; u0 < 2; ++u0) {
    int u = tid + u0 * 256;
    int row = u >> 3, ch = u & 7;
    short8 v = *(const short8*)&vs[((size_t)bh * SEQ + s0 + row) * 64 + ch * 8];
    *(short8*)&lT[row * 80 + ch * 8] = v;
  }
  __syncthreads();
#pragma unroll
  for (int u0 = 0; u0 < 2; ++u0) {
    int u = tid + u0 * 256;
    int o = u >> 3, sc = u & 7;
    short8 w;
#pragma unroll
    for (int j = 0; j < 8; ++j) w[j] = lT[(sc * 8 + j) * 80 + o];
    *(short8*)&vT[((size_t)bh * 64 + o) * SEQ + s0 + sc * 8] = w;
  }
}

// ---------------------------------------------------------------------------
// Kernel 3: causal flash attention, Lorentzian logits, swapped-QK layout.
// Block = (pair of q-tiles {x, 31-x}, bh); 4 waves x 16 q-rows.
// Swapped QK^T (mfma(K,Q) -> S^T): lane (arow,agrp) owns q=arow with
// k = c*16+agrp*4+r. Double-buffered K/V via global_load_lds + counted vmcnt.
// ---------------------------------------------------------------------------
__device__ __forceinline__ void stage_kv(
    const unsigned short* kgp, const unsigned short* vgp,
    unsigned short* dK, unsigned short* dV,
    int k0, int wave, int rl, int chx)
{
  const int r0 = wave * 8 + rl;       // rows 0..31 block
  const int r1 = r0 + 32;             // rows 32..63 block
  GLDS(kgp + (size_t)(k0 + r0) * 64 + chx, dK + wave * 512);
  GLDS(kgp + (size_t)(k0 + r1) * 64 + chx, dK + 2048 + wave * 512);
  GLDS(vgp + (size_t)r0 * SEQ + k0 + chx, dV + wave * 512);
  GLDS(vgp + (size_t)r1 * SEQ + k0 + chx, dV + 2048 + wave * 512);
}

__global__ __launch_bounds__(256) void attn_kernel(
    const unsigned short* __restrict__ qs, const float* __restrict__ qt,
    const unsigned short* __restrict__ ks, const float* __restrict__ ktm,
    const unsigned short* __restrict__ vT, const float* __restrict__ vtm,
    const float* __restrict__ scale_p, float* __restrict__ ctx)
{
  const int xb = blockIdx.x;       // 0..15 -> q-tiles {xb, 31-xb}
  const int bh = blockIdx.y;
  const float a = 2.0f / scale_p[0];

  __shared__ alignas(16) unsigned short lK[2][64 * 64];
  __shared__ alignas(16) unsigned short lV[2][64 * 64];
  __shared__ alignas(16) unsigned short lP[4][16 * 128];   // 256B-stride rows
  __shared__ alignas(16) float lkt[SEQ];
  __shared__ alignas(16) float lvt[SEQ];

  const int tid  = threadIdx.x;
  const int lane = tid & 63;
  const int wave = tid >> 6;
  const int arow = lane & 15;
  const int agrp = lane >> 4;

  const size_t bhbase = (size_t)bh * SEQ;
  const unsigned short* kgp = ks + bhbase * 64;
  const unsigned short* vgp = vT + (size_t)bh * 64 * SEQ;

  const int rl  = lane >> 3;
  const int chx = ((lane & 7) ^ rl) * 8;              // pre-swizzled source slot
  const int dsl0 = (agrp ^ (arow & 7)) * 8;           // kc=0 d-slot (elements)
  const int dsl1 = ((4 + agrp) ^ (arow & 7)) * 8;     // kc=1
  const int swE  = (arow & 15) << 3;                  // P-tile swizzle (elements)
  unsigned short* myP = &lP[wave][0];

  for (int pp = 0; pp < 2; ++pp) {
    const int qb = pp ? (31 - xb) : xb;
    const int q0 = qb * 64;
    const int wq = wave * 16 + arow;

    // Q fragments (stay in registers across the k-loop)
    const unsigned short* qp = qs + (bhbase + q0 + wq) * 64;
    short8 qf0 = *(const short8*)(qp + agrp * 8);
    short8 qf1 = *(const short8*)(qp + 32 + agrp * 8);
    const float aqt = a * qt[bhbase + q0 + wq];

    // stage kt/vt for the whole phase (plain vector copy, broadcast-read later)
#pragma unroll
    for (int i = 0; i < 2; ++i) {
      *(f32x4*)&lkt[tid * 8 + i * 4] = *(const f32x4*)&ktm[bhbase + tid * 8 + i * 4];
      *(f32x4*)&lvt[tid * 8 + i * 4] = *(const f32x4*)&vtm[bhbase + tid * 8 + i * 4];
    }
    // issue tile 0 async loads
    stage_kv(kgp, vgp, lK[0], lV[0], 0, wave, rl, chx);
    asm volatile("s_waitcnt lgkmcnt(0)");   // lkt/lvt writes retired before barrier

    float m_ = -1e30f, lsum = 0.f, ctxt = 0.f;
    f32x4 acc[4] = {};

    for (int kti = 0; kti <= qb; ++kti) {
      const int cur = kti & 1;
      const int k0 = kti * 64;
      if (kti < qb) {
        stage_kv(kgp, vgp, lK[cur ^ 1], lV[cur ^ 1], k0 + 64, wave, rl, chx);
        asm volatile("s_waitcnt vmcnt(4)");   // current tile's 4 loads done
      } else {
        asm volatile("s_waitcnt vmcnt(0)");
      }
      __builtin_amdgcn_s_barrier();           // buf[cur] fully populated

      const unsigned short* Kb = lK[cur];
      const unsigned short* Vb = lV[cur];

      // ---- S^T = K Q^T over 64-dim space part ----
      f32x4 sS[4] = {};
      __builtin_amdgcn_s_setprio(1);
#pragma unroll
      for (int c = 0; c < 4; ++c) {
        short8 kf = *(const short8*)&Kb[(c * 16 + arow) * 64 + dsl0];
        sS[c] = __builtin_amdgcn_mfma_f32_16x16x32_bf16(kf, qf0, sS[c], 0, 0, 0);
      }
#pragma unroll
      for (int c = 0; c < 4; ++c) {
        short8 kf = *(const short8*)&Kb[(c * 16 + arow) * 64 + dsl1];
        sS[c] = __builtin_amdgcn_mfma_f32_16x16x32_bf16(kf, qf1, sS[c], 0, 0, 0);
      }
      __builtin_amdgcn_s_setprio(0);

      // ---- logits: L = a*dot - aqt*kt[k] ----
#pragma unroll
      for (int c = 0; c < 4; ++c) {
        f32x4 kv = *(const f32x4*)&lkt[k0 + c * 16 + agrp * 4];
#pragma unroll
        for (int r = 0; r < 4; ++r)
          sS[c][r] = fmaf(a, sS[c][r], -(aqt * kv[r]));
      }
      if (kti == qb) {   // causal mask on diagonal tile
#pragma unroll
        for (int c = 0; c < 4; ++c)
#pragma unroll
          for (int r = 0; r < 4; ++r)
            if (c * 16 + agrp * 4 + r > wq) sS[c][r] = -1e30f;
      }

      // ---- online softmax (lane owns q=arow; 16 k-values) ----
      float mx0 = fmaxf(fmaxf(sS[0][0], sS[0][1]), fmaxf(sS[0][2], sS[0][3]));
      float mx1 = fmaxf(fmaxf(sS[1][0], sS[1][1]), fmaxf(sS[1][2], sS[1][3]));
      float mx2 = fmaxf(fmaxf(sS[2][0], sS[2][1]), fmaxf(sS[2][2], sS[2][3]));
      float mx3 = fmaxf(fmaxf(sS[3][0], sS[3][1]), fmaxf(sS[3][2], sS[3][3]));
      float mx = fmaxf(fmaxf(mx0, mx1), fmaxf(mx2, mx3));
      mx = fmaxf(mx, __shfl_xor(mx, 16));
      mx = fmaxf(mx, __shfl_xor(mx, 32));
      float mn = fmaxf(m_, mx);
      float fac = __expf(m_ - mn);
      m_ = mn;

      float psum = 0.f, cpart = 0.f;
#pragma unroll
      for (int c = 0; c < 4; ++c) {
        f32x4 vv = *(const f32x4*)&lvt[k0 + c * 16 + agrp * 4];
#pragma unroll
        for (int r = 0; r < 4; ++r) {
          float p = __expf(sS[c][r] - m_);
          sS[c][r] = p;
          psum += p;
          cpart = fmaf(p, vv[r], cpart);
        }
      }
      lsum = lsum * fac + psum;
      ctxt = ctxt * fac + cpart;

      // rescale accumulator (acc rows are q = agrp*4+r -> fetch that row's fac)
#pragma unroll
      for (int r = 0; r < 4; ++r) {
        float facr = __shfl(fac, agrp * 4 + r);
        acc[0][r] *= facr; acc[1][r] *= facr;
        acc[2][r] *= facr; acc[3][r] *= facr;
      }

      // ---- P -> bf16 -> wave-private swizzled LDS (vector writes) ----
#pragma unroll
      for (int c = 0; c < 4; ++c) {
        unsigned int w0 = pk2(sS[c][0], sS[c][1]);
        unsigned int w1 = pk2(sS[c][2], sS[c][3]);
        *(unsigned int*)&myP[arow * 128 + ((c * 16 + agrp * 4) ^ swE)]     = w0;
        *(unsigned int*)&myP[arow * 128 + ((c * 16 + agrp * 4 + 2) ^ swE)] = w1;
      }

      // ---- PV ----
      __builtin_amdgcn_s_setprio(1);
#pragma unroll
      for (int kc = 0; kc < 2; ++kc) {
        short8 pf = *(const short8*)&myP[arow * 128 + ((kc * 32 + agrp * 8) ^ swE)];
        const int dsl = kc ? dsl1 : dsl0;
#pragma unroll
        for (int dc = 0; dc < 4; ++dc) {
          short8 vf = *(const short8*)&Vb[(dc * 16 + arow) * 64 + dsl];
          acc[dc] = __builtin_amdgcn_mfma_f32_16x16x32_bf16(pf, vf, acc[dc], 0, 0, 0);
        }
      }
      __builtin_amdgcn_s_setprio(0);

      __builtin_amdgcn_s_barrier();   // read-done: safe to overwrite buf[cur^1]
    }

    // ---- epilogue ----
    float lsum_t = lsum + __shfl_xor(lsum, 16);
    lsum_t += __shfl_xor(lsum_t, 32);
    float ctxt_t = ctxt + __shfl_xor(ctxt, 16);
    ctxt_t += __shfl_xor(ctxt_t, 32);
    float inv = 1.0f / lsum_t;
    if (agrp == 0)
      ctx[(bhbase + q0 + wave * 16 + arow) * (size_t)DD] = ctxt_t * inv;
#pragma unroll
    for (int r = 0; r < 4; ++r) {
      float invr = __shfl(inv, agrp * 4 + r);
      size_t rb = (bhbase + q0 + wave * 16 + agrp * 4 + r) * (size_t)DD;
#pragma unroll
      for (int dc = 0; dc < 4; ++dc)
        ctx[rb + 1 + dc * 16 + arow] = acc[dc][r] * invr;
    }
  }
}

// ---------------------------------------------------------------------------
// Kernel 4: mean over heads + Lorentz normalization. One wave per (b,s).
// ---------------------------------------------------------------------------
__global__ __launch_bounds__(256) void finalize_kernel(
    const float* __restrict__ ctx, float* __restrict__ out)
{
  const int tid  = threadIdx.x;
  const int lane = tid & 63;
  const int gw = blockIdx.x * 4 + (tid >> 6);
  const int b = gw >> 11, si = gw & (SEQ - 1);
  float v = 0.f, v64 = 0.f;
#pragma unroll
  for (int h = 0; h < NH; ++h) {
    size_t base = ((size_t)(b * NH + h) * SEQ + si) * (size_t)DD;
    v += ctx[base + lane];
    if (lane == 0) v64 += ctx[base + 64];
  }
  float ave   = v * 0.125f;
  float ave64 = v64 * 0.125f;
  float contrib = (lane == 0) ? (ave64 * ave64 - ave * ave) : ave * ave;
  contrib += __shfl_xor(contrib, 1);
  contrib += __shfl_xor(contrib, 2);
  contrib += __shfl_xor(contrib, 4);
  contrib += __shfl_xor(contrib, 8);
  contrib += __shfl_xor(contrib, 16);
  contrib += __shfl_xor(contrib, 32);
  float denom = sqrtf(fmaxf(fabsf(contrib), 1e-8f));
  size_t ob = ((size_t)b * SEQ + si) * (size_t)DD;
  out[ob + lane] = ave / denom;
  if (lane == 0) out[ob + 64] = ave64 / denom;
}

// ---------------------------------------------------------------------------
extern "C" void kernel_launch(void* const* d_in, const int* in_sizes, int n_in,
                              void* d_out, int out_size, void* d_ws, size_t ws_size,
                              hipStream_t stream) {
  const float* Xq  = (const float*)d_in[0];
  const float* Xs  = (const float*)d_in[1];
  const float* Wq  = (const float*)d_in[2];
  const float* Wqb = (const float*)d_in[3];
  const float* Wk  = (const float*)d_in[4];
  const float* Wkb = (const float*)d_in[5];
  const float* Wv  = (const float*)d_in[6];
  const float* Wvb = (const float*)d_in[7];
  const float* scale = (const float*)d_in[8];
  float* out = (float*)d_out;

  char* ws = (char*)d_ws;
  const size_t NROW = (size_t)BATCH * NH * SEQ;   // 65536
  unsigned short* qsb = (unsigned short*)ws; ws += NROW * 64 * 2;
  unsigned short* ksb = (unsigned short*)ws; ws += NROW * 64 * 2;
  unsigned short* vsb = (unsigned short*)ws; ws += NROW * 64 * 2;
  unsigned short* vTb = (unsigned short*)ws; ws += NROW * 64 * 2;
  float* qtb = (float*)ws; ws += NROW * 4;
  float* ktb = (float*)ws; ws += NROW * 4;
  float* vtb = (float*)ws; ws += NROW * 4;
  float* ctx = (float*)ws; ws += NROW * (size_t)DD * 4;

  proj_kernel<<<dim3(128, NH, 3), 256, 0, stream>>>(
      Xq, Xs, Wq, Wqb, Wk, Wkb, Wv, Wvb, qsb, qtb, ksb, ktb, vsb, vtb);
  transpose_v_kernel<<<dim3(SEQ / 64, BATCH * NH), 256, 0, stream>>>(vsb, vTb);
  attn_kernel<<<dim3(16, BATCH * NH), 256, 0, stream>>>(
      qsb, qtb, ksb, ktb, vTb, vtb, scale, ctx);
  finalize_kernel<<<(BATCH * SEQ) / 4, 256, 0, stream>>>(ctx, out);
}

// Round 3
// 111.831 us; speedup vs baseline: 1.6952x; 1.0140x over previous
//
#include <hip/hip_runtime.h>

// Problem constants
#define BATCH 4
#define SEQ   2048
#define INC   512
#define NH    8
#define OUTC  64      // space dim; head dim = 65
#define DD    65

typedef float f32x4 __attribute__((ext_vector_type(4)));
typedef short short8 __attribute__((ext_vector_type(8)));
typedef short short4v __attribute__((ext_vector_type(4)));
typedef unsigned int uint2v __attribute__((ext_vector_type(2)));
typedef unsigned short us;

static __device__ __forceinline__ us f2b(float f) {
  unsigned int u = __float_as_uint(f);
  u = (u + 0x7FFFu + ((u >> 16) & 1u)) >> 16;   // RNE f32->bf16
  return (us)u;
}
static __device__ __forceinline__ float b2f(us h) {
  return __uint_as_float(((unsigned int)h) << 16);
}
static __device__ __forceinline__ unsigned int pk2(float lo, float hi) {
  unsigned int r;
  asm("v_cvt_pk_bf16_f32 %0, %1, %2" : "=v"(r) : "v"(lo), "v"(hi));
  return r;
}

#define GLDS(g, l) __builtin_amdgcn_global_load_lds( \
    (const __attribute__((address_space(1))) void*)(g), \
    (__attribute__((address_space(3))) void*)(l), 16, 0, 0)

// ---------------------------------------------------------------------------
// Kernel 0: f32 -> bf16 conversion for X (both) and W (all three).
// ---------------------------------------------------------------------------
__global__ __launch_bounds__(256) void tobf16_kernel(
    const float* __restrict__ Xq, const float* __restrict__ Xs,
    const float* __restrict__ Wq, const float* __restrict__ Wk,
    const float* __restrict__ Wv,
    us* __restrict__ dXq, us* __restrict__ dXs,
    us* __restrict__ dWq, us* __restrict__ dWk, us* __restrict__ dWv)
{
  const int which = blockIdx.y;
  const float* src;
  us* dst;
  int n;
  switch (which) {
    case 0: src = Xq; dst = dXq; n = BATCH * SEQ * INC; break;
    case 1: src = Xs; dst = dXs; n = BATCH * SEQ * INC; break;
    case 2: src = Wq; dst = dWq; n = NH * OUTC * INC; break;
    case 3: src = Wk; dst = dWk; n = NH * OUTC * INC; break;
    default: src = Wv; dst = dWv; n = NH * OUTC * INC; break;
  }
  for (long i = (long)blockIdx.x * 256 + threadIdx.x; i * 4 < n;
       i += (long)gridDim.x * 256) {
    f32x4 v = *(const f32x4*)(src + i * 4);
    short4v o;
    o[0] = (short)f2b(v[0]); o[1] = (short)f2b(v[1]);
    o[2] = (short)f2b(v[2]); o[3] = (short)f2b(v[3]);
    *(short4v*)(dst + i * 4) = o;
  }
}

// ---------------------------------------------------------------------------
// Kernel 1: per-head projections from bf16 inputs, GLDS double-buffered.
// Outputs: space part bf16 [B,H,S,64]; plus per-kind time outputs:
//   which==0 (Q): qt f32 [B,H,S]
//   which==1 (K): kta bf16 [B,H,S,8] = {-kh,-kl,-kh,0..}
//   which==2 (V): vth/vtl bf16 [B,H,S]
// ---------------------------------------------------------------------------
__global__ __launch_bounds__(256) void proj_kernel(
    const us* __restrict__ Xqb, const us* __restrict__ Xsb,
    const us* __restrict__ Wqb, const us* __restrict__ Wkb, const us* __restrict__ Wvb,
    const float* __restrict__ Bq, const float* __restrict__ Bk, const float* __restrict__ Bv,
    us* __restrict__ qs, float* __restrict__ qt,
    us* __restrict__ ks, us* __restrict__ kta,
    us* __restrict__ vs, us* __restrict__ vth, us* __restrict__ vtl)
{
  const int which = blockIdx.z;
  const us* X = (which == 0) ? Xqb : Xsb;
  const us* W = (which == 0) ? Wqb : (which == 1 ? Wkb : Wvb);
  const float* Bb = (which == 0) ? Bq : (which == 1 ? Bk : Bv);
  us* outs = (which == 0) ? qs : (which == 1 ? ks : vs);

  const int m0 = blockIdx.x * 64;
  const int h  = blockIdx.y;
  const int n0 = h * 64;

  __shared__ alignas(16) us lX[2][64 * 64];
  __shared__ alignas(16) us lW[2][64 * 64];

  const int tid  = threadIdx.x;
  const int lane = tid & 63;
  const int wave = tid >> 6;
  const int arow = lane & 15;
  const int agrp = lane >> 4;
  const int rl   = lane >> 3;
  const int chx  = ((lane & 7) ^ rl) * 8;
  const int r0   = wave * 8 + rl;
  const int r1   = r0 + 32;

#define PSTAGE(buf, k0) do { \
    GLDS(X + (size_t)(m0 + r0) * INC + (k0) + chx, &lX[buf][wave * 512]); \
    GLDS(X + (size_t)(m0 + r1) * INC + (k0) + chx, &lX[buf][2048 + wave * 512]); \
    GLDS(W + (size_t)(n0 + r0) * INC + (k0) + chx, &lW[buf][wave * 512]); \
    GLDS(W + (size_t)(n0 + r1) * INC + (k0) + chx, &lW[buf][2048 + wave * 512]); \
  } while (0)

  f32x4 acc[4] = {};
  PSTAGE(0, 0);

  for (int kk = 0; kk < 8; ++kk) {
    const int cur = kk & 1;
    if (kk < 7) {
      PSTAGE(cur ^ 1, (kk + 1) * 64);
      asm volatile("s_waitcnt vmcnt(4)");
    } else {
      asm volatile("s_waitcnt vmcnt(0)");
    }
    __builtin_amdgcn_s_barrier();
#pragma unroll
    for (int kc = 0; kc < 2; ++kc) {
      short8 af = *(const short8*)&lX[cur][(wave * 16 + arow) * 64 + (((kc * 4 + agrp) ^ (arow & 7)) * 8)];
#pragma unroll
      for (int c = 0; c < 4; ++c) {
        short8 bf = *(const short8*)&lW[cur][(c * 16 + arow) * 64 + (((kc * 4 + agrp) ^ (arow & 7)) * 8)];
        acc[c] = __builtin_amdgcn_mfma_f32_16x16x32_bf16(af, bf, acc[c], 0, 0, 0);
      }
    }
    __builtin_amdgcn_s_barrier();
  }

  float bcol[4];
#pragma unroll
  for (int c = 0; c < 4; ++c) bcol[c] = Bb[n0 + c * 16 + arow];
#pragma unroll
  for (int r = 0; r < 4; ++r) {
    float s2 = 0.f;
#pragma unroll
    for (int c = 0; c < 4; ++c) {
      float v = acc[c][r] + bcol[c];
      acc[c][r] = v;
      s2 += v * v;
    }
    s2 += __shfl_xor(s2, 1); s2 += __shfl_xor(s2, 2);
    s2 += __shfl_xor(s2, 4); s2 += __shfl_xor(s2, 8);
    float tv = sqrtf(s2 + 1.0f);
    int gs = m0 + wave * 16 + agrp * 4 + r;
    int bi = gs >> 11, si = gs & (SEQ - 1);
    size_t rowbase = (size_t)(bi * NH + h) * SEQ + si;
    size_t obase = rowbase * 64;
#pragma unroll
    for (int c = 0; c < 4; ++c) outs[obase + c * 16 + arow] = f2b(acc[c][r]);
    if (arow == 0) {
      if (which == 0) {
        qt[rowbase] = tv;
      } else {
        us th = f2b(tv);
        us tl = f2b(tv - b2f(th));
        if (which == 1) {
          short8 row = {};
          row[0] = (short)(th ^ 0x8000);
          row[1] = (short)(tl ^ 0x8000);
          row[2] = (short)(th ^ 0x8000);
          *(short8*)&kta[rowbase * 8] = row;
        } else {
          vth[rowbase] = th;
          vtl[rowbase] = tl;
        }
      }
    }
  }
}

// ---------------------------------------------------------------------------
// Kernel 2: transpose V space-part per (b,h): [S,64] -> [64,S]  (bf16)
// ---------------------------------------------------------------------------
__global__ __launch_bounds__(256) void transpose_v_kernel(
    const us* __restrict__ vs, us* __restrict__ vT)
{
  const int bh = blockIdx.y;
  const int s0 = blockIdx.x * 64;
  __shared__ us lT[64 * 80];
  const int tid = threadIdx.x;
#pragma unroll
  for (int u0 = 0; u0 < 2; ++u0) {
    int u = tid + u0 * 256;
    int row = u >> 3, ch = u & 7;
    short8 v = *(const short8*)&vs[((size_t)bh * SEQ + s0 + row) * 64 + ch * 8];
    *(short8*)&lT[row * 80 + ch * 8] = v;
  }
  __syncthreads();
#pragma unroll
  for (int u0 = 0; u0 < 2; ++u0) {
    int u = tid + u0 * 256;
    int o = u >> 3, sc = u & 7;
    short8 w;
#pragma unroll
    for (int j = 0; j < 8; ++j) w[j] = lT[(sc * 8 + j) * 80 + o];
    *(short8*)&vT[((size_t)bh * 64 + o) * SEQ + s0 + sc * 8] = w;
  }
}

// ---------------------------------------------------------------------------
// Kernel 3: causal flash attention. Lorentz time-term, P-sum and P*vt are
// all folded into the MFMAs via augmented operands. Swapped QK (mfma(K,Q)).
// ---------------------------------------------------------------------------
__global__ __launch_bounds__(256) void attn_kernel(
    const us* __restrict__ qs, const float* __restrict__ qt,
    const us* __restrict__ ks, const us* __restrict__ kta,
    const us* __restrict__ vT, const us* __restrict__ vth, const us* __restrict__ vtl,
    const float* __restrict__ scale_p, float* __restrict__ ctx)
{
  // XCD-aware swizzle: all 16 q-blocks of a bh land on one XCD.
  const int f = blockIdx.x + 16 * blockIdx.y;
  const int xcd = f & 7, slot = f >> 3;
  const int bh = xcd * 4 + (slot >> 4);
  const int xb = slot & 15;
  const float al2 = (2.0f / scale_p[0]) * 1.44269504088896f;  // a * log2(e)

  __shared__ alignas(16) us lK[2][64 * 64];
  __shared__ alignas(16) us lV[2][64 * 64];
  __shared__ alignas(16) us lKt[2][64 * 8];
  __shared__ alignas(16) us lVt[2][512];       // rows 0/1 = vt hi/lo (first 256B)
  __shared__ alignas(16) us lP[4][16 * 64];

  const int tid  = threadIdx.x;
  const int lane = tid & 63;
  const int wave = tid >> 6;
  const int arow = lane & 15;
  const int agrp = lane >> 4;

  const size_t bhbase = (size_t)bh * SEQ;
  const us* kgp  = ks  + bhbase * 64;
  const us* vgp  = vT  + (size_t)bh * 64 * SEQ;
  const us* ktg  = kta + bhbase * 8;
  const us* vthg = vth + bhbase;
  const us* vtlg = vtl + bhbase;

  const int rl   = lane >> 3;
  const int chx  = ((lane & 7) ^ rl) * 8;
  const int r0s  = wave * 8 + rl;
  const int r1s  = r0s + 32;
  const int dsl0 = (agrp ^ (arow & 7)) * 8;
  const int dsl1 = ((4 + agrp) ^ (arow & 7)) * 8;
  const int swE  = (arow & 7) * 8;
  us* myP = &lP[wave][0];

  const us* vtsrc = (((lane >> 3) & 1) ? vtlg : vthg) + (lane & 7) * 8;

#define ASTAGE(buf, k0) do { \
    GLDS(kgp + (size_t)((k0) + r0s) * 64 + chx, &lK[buf][wave * 512]); \
    GLDS(kgp + (size_t)((k0) + r1s) * 64 + chx, &lK[buf][2048 + wave * 512]); \
    GLDS(vgp + (size_t)r0s * SEQ + (k0) + chx, &lV[buf][wave * 512]); \
    GLDS(vgp + (size_t)r1s * SEQ + (k0) + chx, &lV[buf][2048 + wave * 512]); \
    GLDS(ktg + (size_t)((k0) + lane) * 8, &lKt[buf][0]); \
    GLDS(vtsrc + (k0), &lVt[buf][0]); \
  } while (0)

  short8 ones8;
#pragma unroll
  for (int j = 0; j < 8; ++j) ones8[j] = (short)0x3F80;

  for (int pp = 0; pp < 2; ++pp) {
    const int qb = pp ? (31 - xb) : xb;
    const int q0 = qb * 64;
    const int wq = wave * 16 + arow;

    ASTAGE(0, 0);

    // Q fragments (registers, whole phase)
    const us* qp = qs + (bhbase + q0 + wq) * 64;
    short8 qf0 = *(const short8*)(qp + agrp * 8);
    short8 qf1 = *(const short8*)(qp + 32 + agrp * 8);
    float qtv = qt[bhbase + q0 + wq];
    us qh = f2b(qtv);
    us ql = f2b(qtv - b2f(qh));
    short8 qf2 = {};
    if (agrp == 0) { qf2[0] = (short)qh; qf2[1] = (short)qh; qf2[2] = (short)ql; }

    float m_ = -1e30f;
    f32x4 acc[5] = {};

    for (int kti = 0; kti <= qb; ++kti) {
      const int cur = kti & 1;
      if (kti < qb) {
        ASTAGE(cur ^ 1, (kti + 1) * 64);
        asm volatile("s_waitcnt vmcnt(6)");
      } else {
        asm volatile("s_waitcnt vmcnt(0)");
      }
      __builtin_amdgcn_s_barrier();

      const us* Kb  = lK[cur];
      const us* Vb  = lV[cur];
      const us* Ktb = lKt[cur];
      const us* Vtb = lVt[cur];

      // ---- S^T = K' Q'^T (augmented: includes -qt*kt) ----
      f32x4 sS[4] = {};
      __builtin_amdgcn_s_setprio(1);
#pragma unroll
      for (int c = 0; c < 4; ++c) {
        short8 kf = *(const short8*)&Kb[(c * 16 + arow) * 64 + dsl0];
        sS[c] = __builtin_amdgcn_mfma_f32_16x16x32_bf16(kf, qf0, sS[c], 0, 0, 0);
      }
#pragma unroll
      for (int c = 0; c < 4; ++c) {
        short8 kf = *(const short8*)&Kb[(c * 16 + arow) * 64 + dsl1];
        sS[c] = __builtin_amdgcn_mfma_f32_16x16x32_bf16(kf, qf1, sS[c], 0, 0, 0);
      }
#pragma unroll
      for (int c = 0; c < 4; ++c) {
        short8 kf2 = {};
        if (agrp == 0) kf2 = *(const short8*)&Ktb[(c * 16 + arow) * 8];
        sS[c] = __builtin_amdgcn_mfma_f32_16x16x32_bf16(kf2, qf2, sS[c], 0, 0, 0);
      }
      __builtin_amdgcn_s_setprio(0);

      if (kti == qb) {   // causal mask on diagonal tile
#pragma unroll
        for (int c = 0; c < 4; ++c)
#pragma unroll
          for (int r = 0; r < 4; ++r)
            if (c * 16 + agrp * 4 + r > wq) sS[c][r] = -1e30f;
      }

      // ---- online softmax (lane owns q=arow; 16 k-values) ----
      float mx0 = fmaxf(fmaxf(sS[0][0], sS[0][1]), fmaxf(sS[0][2], sS[0][3]));
      float mx1 = fmaxf(fmaxf(sS[1][0], sS[1][1]), fmaxf(sS[1][2], sS[1][3]));
      float mx2 = fmaxf(fmaxf(sS[2][0], sS[2][1]), fmaxf(sS[2][2], sS[2][3]));
      float mx3 = fmaxf(fmaxf(sS[3][0], sS[3][1]), fmaxf(sS[3][2], sS[3][3]));
      float mx = fmaxf(fmaxf(mx0, mx1), fmaxf(mx2, mx3));
      mx = fmaxf(mx, __shfl_xor(mx, 16));
      mx = fmaxf(mx, __shfl_xor(mx, 32));
      float mn = fmaxf(m_, mx);
      float fac = exp2f(al2 * (m_ - mn));
      m_ = mn;
      float almn = al2 * mn;

#pragma unroll
      for (int c = 0; c < 4; ++c)
#pragma unroll
        for (int r = 0; r < 4; ++r)
          sS[c][r] = exp2f(fmaf(al2, sS[c][r], -almn));

      // rescale all accumulators (incl. time/lsum rows)
#pragma unroll
      for (int r = 0; r < 4; ++r) {
        float facr = __shfl(fac, agrp * 4 + r);
        acc[0][r] *= facr; acc[1][r] *= facr; acc[2][r] *= facr;
        acc[3][r] *= facr; acc[4][r] *= facr;
      }

      // ---- P -> bf16 -> wave-private swizzled LDS (b64 writes) ----
#pragma unroll
      for (int c = 0; c < 4; ++c) {
        uint2v w;
        w[0] = pk2(sS[c][0], sS[c][1]);
        w[1] = pk2(sS[c][2], sS[c][3]);
        *(uint2v*)&myP[arow * 64 + ((c * 16 + agrp * 4) ^ swE)] = w;
      }

      // ---- PV (augmented with [vt_hi, vt_lo, ones] rows -> ctxt & lsum) ----
      __builtin_amdgcn_s_setprio(1);
#pragma unroll
      for (int kc = 0; kc < 2; ++kc) {
        short8 pf = *(const short8*)&myP[arow * 64 + ((kc * 32 + agrp * 8) ^ swE)];
        const int dsl = kc ? dsl1 : dsl0;
#pragma unroll
        for (int dc = 0; dc < 4; ++dc) {
          short8 vf = *(const short8*)&Vb[(dc * 16 + arow) * 64 + dsl];
          acc[dc] = __builtin_amdgcn_mfma_f32_16x16x32_bf16(pf, vf, acc[dc], 0, 0, 0);
        }
        short8 vf4 = {};
        if (arow < 2)  vf4 = *(const short8*)&Vtb[arow * 64 + kc * 32 + agrp * 8];
        if (arow == 2) vf4 = ones8;
        acc[4] = __builtin_amdgcn_mfma_f32_16x16x32_bf16(pf, vf4, acc[4], 0, 0, 0);
      }
      __builtin_amdgcn_s_setprio(0);

      __builtin_amdgcn_s_barrier();   // reads done: safe to overwrite other buf
    }

    // ---- epilogue: lsum/ctxt live in acc[4] (cols 2 / 0+1) ----
#pragma unroll
    for (int r = 0; r < 4; ++r) {
      float ls = __shfl(acc[4][r], (agrp << 4) | 2);
      float t0 = __shfl(acc[4][r], (agrp << 4) | 0);
      float t1 = __shfl(acc[4][r], (agrp << 4) | 1);
      float invr = 1.0f / ls;
      size_t rb = (bhbase + q0 + wave * 16 + agrp * 4 + r) * (size_t)DD;
      if (arow == 0) ctx[rb] = (t0 + t1) * invr;
#pragma unroll
      for (int dc = 0; dc < 4; ++dc)
        ctx[rb + 1 + dc * 16 + arow] = acc[dc][r] * invr;
    }
  }
}

// ---------------------------------------------------------------------------
// Kernel 4: mean over heads + Lorentz normalization. One wave per (b,s).
// ---------------------------------------------------------------------------
__global__ __launch_bounds__(256) void finalize_kernel(
    const float* __restrict__ ctx, float* __restrict__ out)
{
  const int tid  = threadIdx.x;
  const int lane = tid & 63;
  const int gw = blockIdx.x * 4 + (tid >> 6);
  const int b = gw >> 11, si = gw & (SEQ - 1);
  float v = 0.f, v64 = 0.f;
#pragma unroll
  for (int h = 0; h < NH; ++h) {
    size_t base = ((size_t)(b * NH + h) * SEQ + si) * (size_t)DD;
    v += ctx[base + lane];
    if (lane == 0) v64 += ctx[base + 64];
  }
  float ave   = v * 0.125f;
  float ave64 = v64 * 0.125f;
  float contrib = (lane == 0) ? (ave64 * ave64 - ave * ave) : ave * ave;
  contrib += __shfl_xor(contrib, 1);
  contrib += __shfl_xor(contrib, 2);
  contrib += __shfl_xor(contrib, 4);
  contrib += __shfl_xor(contrib, 8);
  contrib += __shfl_xor(contrib, 16);
  contrib += __shfl_xor(contrib, 32);
  float denom = sqrtf(fmaxf(fabsf(contrib), 1e-8f));
  size_t ob = ((size_t)b * SEQ + si) * (size_t)DD;
  out[ob + lane] = ave / denom;
  if (lane == 0) out[ob + 64] = ave64 / denom;
}

// ---------------------------------------------------------------------------
extern "C" void kernel_launch(void* const* d_in, const int* in_sizes, int n_in,
                              void* d_out, int out_size, void* d_ws, size_t ws_size,
                              hipStream_t stream) {
  const float* Xq  = (const float*)d_in[0];
  const float* Xs  = (const float*)d_in[1];
  const float* Wq  = (const float*)d_in[2];
  const float* Bq  = (const float*)d_in[3];
  const float* Wk  = (const float*)d_in[4];
  const float* Bk  = (const float*)d_in[5];
  const float* Wv  = (const float*)d_in[6];
  const float* Bv  = (const float*)d_in[7];
  const float* scale = (const float*)d_in[8];
  float* out = (float*)d_out;

  char* p = (char*)d_ws;
  const size_t NROW = (size_t)BATCH * NH * SEQ;   // 65536

  // Region shared by (Xqb|Xsb) and ctx: proj reads Xb before attn writes ctx.
  float* ctx = (float*)p;
  us* Xqb = (us*)p;
  us* Xsb = (us*)(p + 8388608);
  p += 17040128;                                   // max(16.78MB, 17.04MB) aligned
  us* Wqb16 = (us*)p; p += 524288;
  us* Wkb16 = (us*)p; p += 524288;
  us* Wvb16 = (us*)p; p += 524288;
  us* qsb = (us*)p; p += NROW * 64 * 2;
  us* ksb = (us*)p; p += NROW * 64 * 2;
  us* vsb = (us*)p; p += NROW * 64 * 2;
  us* vTb = (us*)p; p += NROW * 64 * 2;
  float* qtb = (float*)p; p += NROW * 4;
  us* ktaw = (us*)p; p += NROW * 8 * 2;
  us* vthw = (us*)p; p += NROW * 2;
  us* vtlw = (us*)p; p += NROW * 2;

  tobf16_kernel<<<dim3(1024, 5), 256, 0, stream>>>(
      Xq, Xs, Wq, Wk, Wv, Xqb, Xsb, Wqb16, Wkb16, Wvb16);
  proj_kernel<<<dim3(128, NH, 3), 256, 0, stream>>>(
      Xqb, Xsb, Wqb16, Wkb16, Wvb16, Bq, Bk, Bv,
      qsb, qtb, ksb, ktaw, vsb, vthw, vtlw);
  transpose_v_kernel<<<dim3(SEQ / 64, BATCH * NH), 256, 0, stream>>>(vsb, vTb);
  attn_kernel<<<dim3(16, BATCH * NH), 256, 0, stream>>>(
      qsb, qtb, ksb, ktaw, vTb, vthw, vtlw, scale, ctx);
  finalize_kernel<<<(BATCH * SEQ) / 4, 256, 0, stream>>>(ctx, out);
}